// Round 5
// baseline (2445.241 us; speedup 1.0000x reference)
//
#include <hip/hip_runtime.h>
#include <cstdint>

#define K_OFF 27
#define NDOWN 40000
#define NUP   160000
#define CDOWN 128
#define CSKIP 64
#define CCAT  192
#define COUT  96
#define TM    64
#define MT_D  5
#define B_BINS (K_OFF * NUP)      // 4,320,000 bins = total entries for conv

typedef __bf16 bf16x8 __attribute__((ext_vector_type(8)));
typedef float f32x4 __attribute__((ext_vector_type(4)));

__device__ __forceinline__ unsigned short f2b(float f) {
    unsigned int u = __float_as_uint(f);
    u += 0x7FFFu + ((u >> 16) & 1u);           // round-to-nearest-even
    return (unsigned short)(u >> 16);
}
__device__ __forceinline__ unsigned int pk2(float a, float b) {
    return (unsigned)f2b(a) | ((unsigned)f2b(b) << 16);
}

__device__ __forceinline__ void gll16(const void* gsrc, void* ldst) {
    auto g = reinterpret_cast<const __attribute__((address_space(1))) unsigned int*>(
        reinterpret_cast<uintptr_t>(gsrc));
    auto l = reinterpret_cast<__attribute__((address_space(3))) unsigned int*>(
        reinterpret_cast<uintptr_t>(ldst));
    __builtin_amdgcn_global_load_lds(g, l, 16, 0, 0);
}

// ---------------- fused precompute: down->bf16, WdT, WcT ----------------
__global__ void pack_all_kernel(const float* __restrict__ down,
                                const float* __restrict__ Wd,
                                const float* __restrict__ Wc,
                                unsigned short* __restrict__ dbf,
                                unsigned short* __restrict__ WdT,
                                unsigned short* __restrict__ WcT) {
    int i = blockIdx.x * 256 + threadIdx.x;          // grid = 2500*256 = 640000
    if (i < NDOWN * CDOWN / 8) {
        const float4* s = (const float4*)down + (long)i * 2;
        float4 v0 = s[0], v1 = s[1];
        uint4 o;
        o.x = pk2(v0.x, v0.y); o.y = pk2(v0.z, v0.w);
        o.z = pk2(v1.x, v1.y); o.w = pk2(v1.z, v1.w);
        ((uint4*)dbf)[i] = o;
    }
    if (i < K_OFF * CDOWN * CDOWN) {
        int k = i / (CDOWN * CDOWN), rem = i % (CDOWN * CDOWN);
        int n = rem >> 7, c = rem & 127;
        WdT[i] = f2b(Wd[((long)k * CDOWN + c) * CDOWN + n]);
    }
    if (i < K_OFF * COUT * CCAT) {
        int k = i / (COUT * CCAT), rem = i % (COUT * CCAT);
        int n = rem / CCAT, c = rem % CCAT;
        WcT[i] = f2b(Wc[((long)k * CCAT + c) * COUT + n]);
    }
}

// cat[j][0:128] = bf16(relu(up[j])), cat[j][128:192] = bf16(skip[j])
__global__ void pack_cat_kernel(const float* __restrict__ up, const float* __restrict__ skip,
                                unsigned short* __restrict__ cat) {
    const int t = threadIdx.x;                       // 192 threads, 8 rows/block
    const int j = blockIdx.x * 8 + t / 24;
    const int s = t % 24;
    const int e0 = s * 8;
    float4 v0, v1;
    if (e0 < CDOWN) {
        const float4* src = (const float4*)(up + (long)j * CDOWN + e0);
        v0 = src[0]; v1 = src[1];
        v0.x = fmaxf(v0.x, 0.f); v0.y = fmaxf(v0.y, 0.f);
        v0.z = fmaxf(v0.z, 0.f); v0.w = fmaxf(v0.w, 0.f);
        v1.x = fmaxf(v1.x, 0.f); v1.y = fmaxf(v1.y, 0.f);
        v1.z = fmaxf(v1.z, 0.f); v1.w = fmaxf(v1.w, 0.f);
    } else {
        const float4* src = (const float4*)(skip + (long)j * CSKIP + (e0 - CDOWN));
        v0 = src[0]; v1 = src[1];
    }
    uint4 o;
    o.x = pk2(v0.x, v0.y); o.y = pk2(v0.z, v0.w);
    o.z = pk2(v1.x, v1.y); o.w = pk2(v1.z, v1.w);
    ((uint4*)(cat + (long)j * CCAT))[s] = o;
}

// ---------------- deconv (scatter form, verified rounds 2/4) ----------------
__global__ __launch_bounds__(256, 2)
void deconv_fast(const unsigned short* __restrict__ dbf,
                 const unsigned short* __restrict__ WdT,
                 const int* __restrict__ in_idx,
                 const int* __restrict__ out_idx,
                 float* __restrict__ up) {
    __shared__ __align__(1024) unsigned short sA[TM * CDOWN];

    const int segs = (NDOWN / TM) / MT_D;
    const int bk = blockIdx.x / segs;
    const int tile0 = (blockIdx.x % segs) * MT_D;
    const int t = threadIdx.x;
    const int wave = t >> 6, lane = t & 63;
    const int col = lane & 15, quad = lane >> 4;
    const int wm = wave & 1, wn = wave >> 1;

    int srow[4], soff[4];
#pragma unroll
    for (int i = 0; i < 4; i++) {
        int c = wave * 256 + i * 64 + lane;
        int r = c >> 4, cc = c & 15;
        srow[i] = r;
        soff[i] = (cc ^ (r & 7)) * 16;
    }

    bf16x8 b[4][4];
    {
        const unsigned short* wb = WdT + (long)bk * CDOWN * CDOWN;
#pragma unroll
        for (int kk = 0; kk < 4; kk++)
#pragma unroll
            for (int nt = 0; nt < 4; nt++)
                b[kk][nt] = *(const bf16x8*)&wb[(wn * 64 + nt * 16 + col) * CDOWN + kk * 32 + quad * 8];
    }

    const long kBase = (long)bk * NDOWN;
    const char* sAc = (const char*)sA;

    for (int tt = 0; tt < MT_D; ++tt) {
        const int rowbase = (tile0 + tt) * TM;
#pragma unroll
        for (int i = 0; i < 4; i++) {
            const int j = in_idx[kBase + rowbase + srow[i]];
            gll16((const char*)dbf + (long)j * (CDOWN * 2) + soff[i],
                  (char*)sA + (wave * 4 + i) * 1024);
        }
        __syncthreads();

        f32x4 acc[2][4];
#pragma unroll
        for (int mi = 0; mi < 2; mi++)
#pragma unroll
            for (int nt = 0; nt < 4; nt++) acc[mi][nt] = (f32x4){0.f, 0.f, 0.f, 0.f};

#pragma unroll
        for (int kk = 0; kk < 4; kk++) {
            const int ch = kk * 4 + quad;
#pragma unroll
            for (int mi = 0; mi < 2; mi++) {
                const int row = wm * 32 + mi * 16 + col;
                bf16x8 a = *(const bf16x8*)(sAc + row * 256 + ((ch ^ (row & 7)) * 16));
#pragma unroll
                for (int nt = 0; nt < 4; nt++)
                    acc[mi][nt] = __builtin_amdgcn_mfma_f32_16x16x32_bf16(a, b[kk][nt], acc[mi][nt], 0, 0, 0);
            }
        }
        __syncthreads();

#pragma unroll
        for (int mi = 0; mi < 2; mi++)
#pragma unroll
            for (int r = 0; r < 4; r++) {
                const int lrow = wm * 32 + mi * 16 + quad * 4 + r;
                const long ob = (long)out_idx[kBase + rowbase + lrow] * CDOWN;
#pragma unroll
                for (int nt = 0; nt < 4; nt++)
                    atomicAdd(&up[ob + wn * 64 + nt * 16 + col], acc[mi][nt][r]);
            }
    }
}

// ---------------- inverse-CSR build ----------------
__global__ void hist_kernel(const int* __restrict__ cv_out, unsigned int* __restrict__ hist) {
    const int i = blockIdx.x * 256 + threadIdx.x;
    const int k = blockIdx.y;
    const int j = cv_out[(long)k * NUP + i];
    atomicAdd(&hist[(long)k * NUP + j], 1u);
}

__global__ void scan_blocks(const unsigned int* __restrict__ in, unsigned int* __restrict__ out,
                            unsigned int* __restrict__ aux, int n) {
    __shared__ unsigned int ls[256];
    const int t = threadIdx.x;
    const long base = (long)blockIdx.x * 1024 + (long)t * 4;
    unsigned int v0 = (base     < n) ? in[base]     : 0u;
    unsigned int v1 = (base + 1 < n) ? in[base + 1] : 0u;
    unsigned int v2 = (base + 2 < n) ? in[base + 2] : 0u;
    unsigned int v3 = (base + 3 < n) ? in[base + 3] : 0u;
    const unsigned int s = v0 + v1 + v2 + v3;
    ls[t] = s;
    __syncthreads();
    for (int off = 1; off < 256; off <<= 1) {
        unsigned int x = (t >= off) ? ls[t - off] : 0u;
        __syncthreads();
        ls[t] += x;
        __syncthreads();
    }
    const unsigned int ex = ls[t] - s;
    if (base     < n) out[base]     = ex;
    if (base + 1 < n) out[base + 1] = ex + v0;
    if (base + 2 < n) out[base + 2] = ex + v0 + v1;
    if (base + 3 < n) out[base + 3] = ex + v0 + v1 + v2;
    if (aux != nullptr && t == 255) aux[blockIdx.x] = ls[255];
}

// fused mid-level: in-place exclusive scan of aux1 (n ~ 4219), single block
__global__ void scan_mid(unsigned int* __restrict__ a, int n) {
    __shared__ unsigned int ls[256];
    __shared__ unsigned int carry;
    const int t = threadIdx.x;
    if (t == 0) carry = 0u;
    __syncthreads();
    for (int base = 0; base < n; base += 256) {
        const int idx = base + t;
        unsigned int v = (idx < n) ? a[idx] : 0u;
        ls[t] = v;
        __syncthreads();
        for (int off = 1; off < 256; off <<= 1) {
            unsigned int x = (t >= off) ? ls[t - off] : 0u;
            __syncthreads();
            ls[t] += x;
            __syncthreads();
        }
        const unsigned int ex = ls[t] - v + carry;
        if (idx < n) a[idx] = ex;
        __syncthreads();
        if (t == 0) carry += ls[255];
        __syncthreads();
    }
}

__global__ void addback_kernel(unsigned int* __restrict__ out, const unsigned int* __restrict__ aux, int n) {
    const long i = (long)blockIdx.x * 256 + threadIdx.x;
    if (i < n) out[i] += aux[i >> 10];
}

__global__ void scatter_kernel(const int* __restrict__ cv_in,
                               const int* __restrict__ cv_out,
                               const unsigned int* __restrict__ start,
                               unsigned int* __restrict__ hist,       // counts, consumed
                               unsigned int* __restrict__ entries) {
    const int i = blockIdx.x * 256 + threadIdx.x;
    const int k = blockIdx.y;
    const long p = (long)k * NUP + i;
    const int j = cv_out[p];
    const long bin = (long)k * NUP + j;
    const unsigned int off = atomicSub(&hist[bin], 1u) - 1u;
    entries[start[bin] + off] = (unsigned int)cv_in[p];
}

// ---------------- conv v2: gather form, zero scratch arrays, dbuf LDS, B in regs per kk ----------------
__global__ __launch_bounds__(256, 3)
void conv_inv(const unsigned short* __restrict__ cat,
              const unsigned short* __restrict__ WcT,
              const unsigned int* __restrict__ start,
              const unsigned int* __restrict__ entries,
              float* __restrict__ out) {
    __shared__ __align__(1024) unsigned short sA[2][TM * CCAT];   // 48 KB double-buffered A

    const int j0 = blockIdx.x * TM;
    const int t = threadIdx.x;
    const int wave = t >> 6, lane = t & 63;
    const int col = lane & 15, quad = lane >> 4;
    const int wm = wave & 1, wn = wave >> 1;
    const int r  = t >> 2;           // staging row 0..63 (4 threads/row)
    const int cq = (t & 3) * 6;      // staging chunk base (6 chunks of 16B)

    f32x4 acc[2][3];
#pragma unroll
    for (int mi = 0; mi < 2; mi++)
#pragma unroll
        for (int nt = 0; nt < 3; nt++) acc[mi][nt] = (f32x4){0.f, 0.f, 0.f, 0.f};

    // stream one A tile (kernel offset kp) into buffer `buf`, chunk-at-a-time (no arrays)
    auto produce = [&](int kp, int buf) {
        char* dst = (char*)sA[buf] + r * 384;
        const long kb = (long)kp * NUP;
        const unsigned int s0 = start[kb + j0 + r];
        const long nx = kb + j0 + r + 1;
        const unsigned int s1 = (nx == (long)B_BINS) ? (unsigned int)B_BINS : start[nx];
        const unsigned int n = s1 - s0;
        if (n == 1u) {                               // common: straight bf16 chunk copies
            const uint4* src = (const uint4*)(cat + (long)entries[s0] * CCAT) + cq;
#pragma unroll
            for (int q = 0; q < 6; q++) {
                uint4 v = src[q];
                *(uint4*)(dst + (((cq + q) ^ (r & 7)) << 4)) = v;
            }
        } else if (n == 0u) {
            const uint4 z = make_uint4(0u, 0u, 0u, 0u);
#pragma unroll
            for (int q = 0; q < 6; q++)
                *(uint4*)(dst + (((cq + q) ^ (r & 7)) << 4)) = z;
        } else {                                     // duplicates: f32 sum per chunk
#pragma unroll
            for (int q = 0; q < 6; q++) {
                float fa[8];
#pragma unroll
                for (int e8 = 0; e8 < 8; e8++) fa[e8] = 0.f;
                for (unsigned int e = s0; e < s1; e++) {
                    const uint4 c = ((const uint4*)(cat + (long)entries[e] * CCAT))[cq + q];
                    fa[0] += __uint_as_float(c.x << 16); fa[1] += __uint_as_float(c.x & 0xffff0000u);
                    fa[2] += __uint_as_float(c.y << 16); fa[3] += __uint_as_float(c.y & 0xffff0000u);
                    fa[4] += __uint_as_float(c.z << 16); fa[5] += __uint_as_float(c.z & 0xffff0000u);
                    fa[6] += __uint_as_float(c.w << 16); fa[7] += __uint_as_float(c.w & 0xffff0000u);
                }
                uint4 o;
                o.x = pk2(fa[0], fa[1]); o.y = pk2(fa[2], fa[3]);
                o.z = pk2(fa[4], fa[5]); o.w = pk2(fa[6], fa[7]);
                *(uint4*)(dst + (((cq + q) ^ (r & 7)) << 4)) = o;
            }
        }
    };

    produce(0, 0);

    // per-lane B base: row (wn*48 + nt*16 + col), K bytes at kk*32 + quad*8 elems
    const unsigned short* wl = WcT + (long)(wn * 48 + col) * CCAT + quad * 8;
    const int row0 = wm * 32 + col, row1 = row0 + 16;

    for (int k = 0; k < K_OFF; k++) {
        __syncthreads();                              // tile k visible; buf (k+1)&1 free
        if (k + 1 < K_OFF) produce(k + 1, (k + 1) & 1);
        const unsigned short* wk = wl + (long)k * (COUT * CCAT);
        const char* cur = (const char*)sA[k & 1];
#pragma unroll
        for (int kk = 0; kk < 6; kk++) {
            bf16x8 b0 = *(const bf16x8*)(wk + kk * 32);
            bf16x8 b1 = *(const bf16x8*)(wk + 16 * CCAT + kk * 32);
            bf16x8 b2 = *(const bf16x8*)(wk + 32 * CCAT + kk * 32);
            const int c2 = kk * 4 + quad;
            bf16x8 a0 = *(const bf16x8*)(cur + row0 * 384 + ((c2 ^ (row0 & 7)) << 4));
            bf16x8 a1 = *(const bf16x8*)(cur + row1 * 384 + ((c2 ^ (row1 & 7)) << 4));
            acc[0][0] = __builtin_amdgcn_mfma_f32_16x16x32_bf16(a0, b0, acc[0][0], 0, 0, 0);
            acc[1][0] = __builtin_amdgcn_mfma_f32_16x16x32_bf16(a1, b0, acc[1][0], 0, 0, 0);
            acc[0][1] = __builtin_amdgcn_mfma_f32_16x16x32_bf16(a0, b1, acc[0][1], 0, 0, 0);
            acc[1][1] = __builtin_amdgcn_mfma_f32_16x16x32_bf16(a1, b1, acc[1][1], 0, 0, 0);
            acc[0][2] = __builtin_amdgcn_mfma_f32_16x16x32_bf16(a0, b2, acc[0][2], 0, 0, 0);
            acc[1][2] = __builtin_amdgcn_mfma_f32_16x16x32_bf16(a1, b2, acc[1][2], 0, 0, 0);
        }
    }

    // fused ReLU + plain coalesced stores, full coverage (no memset of out needed)
#pragma unroll
    for (int mi = 0; mi < 2; mi++)
#pragma unroll
        for (int rr = 0; rr < 4; rr++) {
            const int lrow = wm * 32 + mi * 16 + quad * 4 + rr;
            float* op = out + (long)(j0 + lrow) * COUT + wn * 48 + col;
#pragma unroll
            for (int nt = 0; nt < 3; nt++)
                op[nt * 16] = fmaxf(acc[mi][nt][rr], 0.f);
        }
}

// ================= fallback path (ws too small) =================
#define SA1 136
#define SB1 136

__global__ __launch_bounds__(256, 2)
void deconv_kernel(const float* __restrict__ down,
                   const float* __restrict__ Wd,
                   const int* __restrict__ in_idx,
                   const int* __restrict__ out_idx,
                   float* __restrict__ up) {
    __shared__ __align__(16) unsigned short sA[TM * SA1];
    __shared__ __align__(16) unsigned short sB[CDOWN * SB1];
    __shared__ int sOut[TM];

    const int tiles = NDOWN / TM;
    const int bk = blockIdx.x / tiles;
    const int tile = blockIdx.x % tiles;
    const int t = threadIdx.x;
    const long kInBase = (long)bk * NDOWN + tile * TM;

    {
        const int r = t >> 2;
        const int c0 = (t & 3) * 32;
        const int j = in_idx[kInBase + r];
        const float* src = down + (long)j * CDOWN + c0;
        unsigned short* dst = sA + r * SA1 + c0;
        #pragma unroll
        for (int c = 0; c < 32; c += 4) {
            float4 v = *(const float4*)(src + c);
            *(unsigned int*)(dst + c)     = pk2(v.x, v.y);
            *(unsigned int*)(dst + c + 2) = pk2(v.z, v.w);
        }
    }
    {
        const float* wsrc = Wd + (long)bk * CDOWN * CDOWN;
        for (int idx = t; idx < CDOWN * CDOWN; idx += 256) {
            const int kk = idx >> 7;
            const int n  = idx & 127;
            sB[n * SB1 + kk] = f2b(wsrc[idx]);
        }
    }
    if (t < TM) sOut[t] = out_idx[kInBase + t];
    __syncthreads();

    const int wave = t >> 6;
    const int lane = t & 63;
    const int col  = lane & 15;
    const int quad = lane >> 4;
    const int mrow = wave * 16 + col;

    f32x4 acc[8];
    #pragma unroll
    for (int i = 0; i < 8; i++) acc[i] = (f32x4){0.f, 0.f, 0.f, 0.f};

    #pragma unroll
    for (int k0 = 0; k0 < CDOWN; k0 += 32) {
        const int koff = k0 + quad * 8;
        bf16x8 a = *(const bf16x8*)&sA[mrow * SA1 + koff];
        #pragma unroll
        for (int nt = 0; nt < 8; nt++) {
            bf16x8 bb = *(const bf16x8*)&sB[(nt * 16 + col) * SB1 + koff];
            acc[nt] = __builtin_amdgcn_mfma_f32_16x16x32_bf16(a, bb, acc[nt], 0, 0, 0);
        }
    }
    #pragma unroll
    for (int r = 0; r < 4; r++) {
        const int lrow = wave * 16 + quad * 4 + r;
        const long obase = (long)sOut[lrow] * CDOWN;
        #pragma unroll
        for (int nt = 0; nt < 8; nt++)
            atomicAdd(&up[obase + nt * 16 + col], acc[nt][r]);
    }
}

#define SA2 200
#define SB2 200

__global__ __launch_bounds__(256, 2)
void conv_kernel(const float* __restrict__ up,
                 const float* __restrict__ skip,
                 const float* __restrict__ Wc,
                 const int* __restrict__ in_idx,
                 const int* __restrict__ out_idx,
                 float* __restrict__ out) {
    __shared__ __align__(16) unsigned short sA[TM * SA2];
    __shared__ __align__(16) unsigned short sB[COUT * SB2];
    __shared__ int sOut[TM];

    const int tiles = NUP / TM;
    const int bk = blockIdx.x / tiles;
    const int tile = blockIdx.x % tiles;
    const int t = threadIdx.x;
    const long kInBase = (long)bk * NUP + tile * TM;

    {
        const int r = t >> 2;
        const int c0 = (t & 3) * 48;
        const int j = in_idx[kInBase + r];
        const float* uprow = up + (long)j * CDOWN;
        const float* skrow = skip + (long)j * CSKIP;
        unsigned short* dst = sA + r * SA2 + c0;
        #pragma unroll
        for (int c = 0; c < 48; c += 4) {
            const int gc = c0 + c;
            float4 v;
            if (gc < CDOWN) {
                v = *(const float4*)(uprow + gc);
                v.x = fmaxf(v.x, 0.f); v.y = fmaxf(v.y, 0.f);
                v.z = fmaxf(v.z, 0.f); v.w = fmaxf(v.w, 0.f);
            } else {
                v = *(const float4*)(skrow + (gc - CDOWN));
            }
            *(unsigned int*)(dst + c)     = pk2(v.x, v.y);
            *(unsigned int*)(dst + c + 2) = pk2(v.z, v.w);
        }
    }
    {
        const float* wsrc = Wc + (long)bk * CCAT * COUT;
        for (int idx = t; idx < CCAT * COUT; idx += 256) {
            const int kk = idx / COUT;
            const int n  = idx - kk * COUT;
            sB[n * SB2 + kk] = f2b(wsrc[idx]);
        }
    }
    if (t < TM) sOut[t] = out_idx[kInBase + t];
    __syncthreads();

    const int wave = t >> 6;
    const int lane = t & 63;
    const int col  = lane & 15;
    const int quad = lane >> 4;
    const int mrow = wave * 16 + col;

    f32x4 acc[6];
    #pragma unroll
    for (int i = 0; i < 6; i++) acc[i] = (f32x4){0.f, 0.f, 0.f, 0.f};

    #pragma unroll
    for (int k0 = 0; k0 < CCAT; k0 += 32) {
        const int koff = k0 + quad * 8;
        bf16x8 a = *(const bf16x8*)&sA[mrow * SA2 + koff];
        #pragma unroll
        for (int nt = 0; nt < 6; nt++) {
            bf16x8 bb = *(const bf16x8*)&sB[(nt * 16 + col) * SB2 + koff];
            acc[nt] = __builtin_amdgcn_mfma_f32_16x16x32_bf16(a, bb, acc[nt], 0, 0, 0);
        }
    }
    #pragma unroll
    for (int r = 0; r < 4; r++) {
        const int lrow = wave * 16 + quad * 4 + r;
        const long obase = (long)sOut[lrow] * COUT;
        #pragma unroll
        for (int nt = 0; nt < 6; nt++)
            atomicAdd(&out[obase + nt * 16 + col], acc[nt][r]);
    }
}

__global__ void relu_kernel(float* __restrict__ x, int n4) {
    int i = blockIdx.x * blockDim.x + threadIdx.x;
    if (i < n4) {
        float4 v = ((float4*)x)[i];
        v.x = fmaxf(v.x, 0.f); v.y = fmaxf(v.y, 0.f);
        v.z = fmaxf(v.z, 0.f); v.w = fmaxf(v.w, 0.f);
        ((float4*)x)[i] = v;
    }
}

extern "C" void kernel_launch(void* const* d_in, const int* in_sizes, int n_in,
                              void* d_out, int out_size, void* d_ws, size_t ws_size,
                              hipStream_t stream) {
    const float* skip   = (const float*)d_in[0];
    const float* down   = (const float*)d_in[1];
    const float* Wd     = (const float*)d_in[2];
    const float* Wc     = (const float*)d_in[3];
    const int* dc_in    = (const int*)d_in[4];
    const int* dc_out   = (const int*)d_in[5];
    const int* cv_in    = (const int*)d_in[6];
    const int* cv_out   = (const int*)d_in[7];
    float* out = (float*)d_out;
    float* up  = (float*)d_ws;                   // [NUP][CDOWN] f32, dead after pack_cat

    const size_t OFF_CAT = (size_t)NUP * CDOWN * 4;                    //  81,920,000
    const size_t OFF_DBF = OFF_CAT + (size_t)NUP * CCAT * 2;           // 143,360,000
    const size_t OFF_WDT = OFF_DBF + (size_t)NDOWN * CDOWN * 2;        // 153,600,000
    const size_t OFF_WCT = OFF_WDT + (size_t)K_OFF * CDOWN * CDOWN * 2;// 154,484,736
    const size_t WS_NEED = OFF_WCT + (size_t)K_OFF * COUT * CCAT * 2;  // 155,480,064

    hipMemsetAsync(up, 0, (size_t)NUP * CDOWN * sizeof(float), stream);

    if (ws_size >= WS_NEED) {
        unsigned short* catb = (unsigned short*)((char*)d_ws + OFF_CAT);
        unsigned short* dbf  = (unsigned short*)((char*)d_ws + OFF_DBF);
        unsigned short* WdT  = (unsigned short*)((char*)d_ws + OFF_WDT);
        unsigned short* WcT  = (unsigned short*)((char*)d_ws + OFF_WCT);

        // CSR scratch overlays the `up` region (touched only AFTER pack_cat);
        // histogram overlays d_out (conv_inv rewrites every element afterwards).
        unsigned int* entriesC = (unsigned int*)d_ws;                           // 17.28 MB
        unsigned int* startC   = (unsigned int*)((char*)d_ws + 17280000);       // 17.28 MB
        unsigned int* aux1     = (unsigned int*)((char*)d_ws + 34560000);       // 4219*4 B
        unsigned int* hist     = (unsigned int*)d_out;                          // 17.28 MB

        pack_all_kernel<<<2500, 256, 0, stream>>>(down, Wd, Wc, dbf, WdT, WcT);
        deconv_fast<<<K_OFF * ((NDOWN / TM) / MT_D), 256, 0, stream>>>(dbf, WdT, dc_in, dc_out, up);
        pack_cat_kernel<<<NUP / 8, 192, 0, stream>>>(up, skip, catb);
        // ---- up region now dead; build inverse CSR for conv ----
        hipMemsetAsync(hist, 0, (size_t)B_BINS * 4, stream);
        hist_kernel<<<dim3(NUP / 256, K_OFF), 256, 0, stream>>>(cv_out, hist);
        const int nblk1 = (B_BINS + 1023) / 1024;                // 4219
        scan_blocks<<<nblk1, 256, 0, stream>>>(hist, startC, aux1, B_BINS);
        scan_mid<<<1, 256, 0, stream>>>(aux1, nblk1);
        addback_kernel<<<(B_BINS + 255) / 256, 256, 0, stream>>>(startC, aux1, B_BINS);
        scatter_kernel<<<dim3(NUP / 256, K_OFF), 256, 0, stream>>>(cv_in, cv_out, startC, hist, entriesC);
        // ---- gather-form conv: no atomics, fused ReLU, full-coverage stores ----
        conv_inv<<<NUP / TM, 256, 0, stream>>>(catb, WcT, startC, entriesC, out);
    } else {
        hipMemsetAsync(out, 0, (size_t)out_size * sizeof(float), stream);
        deconv_kernel<<<K_OFF * (NDOWN / TM), 256, 0, stream>>>(down, Wd, dc_in, dc_out, up);
        conv_kernel<<<K_OFF * (NUP / TM), 256, 0, stream>>>(up, skip, Wc, cv_in, cv_out, out);
        relu_kernel<<<(out_size / 4 + 255) / 256, 256, 0, stream>>>(out, out_size / 4);
    }
}

// Round 7
// 2006.552 us; speedup vs baseline: 1.2186x; 1.2186x over previous
//
#include <hip/hip_runtime.h>
#include <cstdint>

#define K_OFF 27
#define NDOWN 40000
#define NUP   160000
#define CDOWN 128
#define CSKIP 64
#define CCAT  192
#define COUT  96
#define TM    64
#define MT_D  5
#define B_BINS (K_OFF * NUP)      // 4,320,000 bins = total entries for conv

typedef __bf16 bf16x8 __attribute__((ext_vector_type(8)));
typedef float f32x4 __attribute__((ext_vector_type(4)));

__device__ __forceinline__ unsigned short f2b(float f) {
    unsigned int u = __float_as_uint(f);
    u += 0x7FFFu + ((u >> 16) & 1u);           // round-to-nearest-even
    return (unsigned short)(u >> 16);
}
__device__ __forceinline__ unsigned int pk2(float a, float b) {
    return (unsigned)f2b(a) | ((unsigned)f2b(b) << 16);
}

__device__ __forceinline__ void gll16(const void* gsrc, void* ldst) {
    auto g = reinterpret_cast<const __attribute__((address_space(1))) unsigned int*>(
        reinterpret_cast<uintptr_t>(gsrc));
    auto l = reinterpret_cast<__attribute__((address_space(3))) unsigned int*>(
        reinterpret_cast<uintptr_t>(ldst));
    __builtin_amdgcn_global_load_lds(g, l, 16, 0, 0);
}

// add one bf16x8 chunk (as uint4) into 8 f32 accumulators
__device__ __forceinline__ void addchunk(float* fa, uint4 c) {
    fa[0] += __uint_as_float(c.x << 16); fa[1] += __uint_as_float(c.x & 0xffff0000u);
    fa[2] += __uint_as_float(c.y << 16); fa[3] += __uint_as_float(c.y & 0xffff0000u);
    fa[4] += __uint_as_float(c.z << 16); fa[5] += __uint_as_float(c.z & 0xffff0000u);
    fa[6] += __uint_as_float(c.w << 16); fa[7] += __uint_as_float(c.w & 0xffff0000u);
}

// ---------------- fused precompute: down->bf16, WdT, WcT ----------------
__global__ void pack_all_kernel(const float* __restrict__ down,
                                const float* __restrict__ Wd,
                                const float* __restrict__ Wc,
                                unsigned short* __restrict__ dbf,
                                unsigned short* __restrict__ WdT,
                                unsigned short* __restrict__ WcT) {
    int i = blockIdx.x * 256 + threadIdx.x;          // grid = 2500*256 = 640000
    if (i < NDOWN * CDOWN / 8) {
        const float4* s = (const float4*)down + (long)i * 2;
        float4 v0 = s[0], v1 = s[1];
        uint4 o;
        o.x = pk2(v0.x, v0.y); o.y = pk2(v0.z, v0.w);
        o.z = pk2(v1.x, v1.y); o.w = pk2(v1.z, v1.w);
        ((uint4*)dbf)[i] = o;
    }
    if (i < K_OFF * CDOWN * CDOWN) {
        int k = i / (CDOWN * CDOWN), rem = i % (CDOWN * CDOWN);
        int n = rem >> 7, c = rem & 127;
        WdT[i] = f2b(Wd[((long)k * CDOWN + c) * CDOWN + n]);
    }
    if (i < K_OFF * COUT * CCAT) {
        int k = i / (COUT * CCAT), rem = i % (COUT * CCAT);
        int n = rem / CCAT, c = rem % CCAT;
        WcT[i] = f2b(Wc[((long)k * CCAT + c) * COUT + n]);
    }
}

// cat[j][0:128] = bf16(relu(up[j])), cat[j][128:192] = bf16(skip[j])
__global__ void pack_cat_kernel(const float* __restrict__ up, const float* __restrict__ skip,
                                unsigned short* __restrict__ cat) {
    const int t = threadIdx.x;                       // 192 threads, 8 rows/block
    const int j = blockIdx.x * 8 + t / 24;
    const int s = t % 24;
    const int e0 = s * 8;
    float4 v0, v1;
    if (e0 < CDOWN) {
        const float4* src = (const float4*)(up + (long)j * CDOWN + e0);
        v0 = src[0]; v1 = src[1];
        v0.x = fmaxf(v0.x, 0.f); v0.y = fmaxf(v0.y, 0.f);
        v0.z = fmaxf(v0.z, 0.f); v0.w = fmaxf(v0.w, 0.f);
        v1.x = fmaxf(v1.x, 0.f); v1.y = fmaxf(v1.y, 0.f);
        v1.z = fmaxf(v1.z, 0.f); v1.w = fmaxf(v1.w, 0.f);
    } else {
        const float4* src = (const float4*)(skip + (long)j * CSKIP + (e0 - CDOWN));
        v0 = src[0]; v1 = src[1];
    }
    uint4 o;
    o.x = pk2(v0.x, v0.y); o.y = pk2(v0.z, v0.w);
    o.z = pk2(v1.x, v1.y); o.w = pk2(v1.z, v1.w);
    ((uint4*)(cat + (long)j * CCAT))[s] = o;
}

// ---------------- deconv (scatter form, verified rounds 2/4/5) ----------------
__global__ __launch_bounds__(256, 2)
void deconv_fast(const unsigned short* __restrict__ dbf,
                 const unsigned short* __restrict__ WdT,
                 const int* __restrict__ in_idx,
                 const int* __restrict__ out_idx,
                 float* __restrict__ up) {
    __shared__ __align__(1024) unsigned short sA[TM * CDOWN];

    const int segs = (NDOWN / TM) / MT_D;
    const int bk = blockIdx.x / segs;
    const int tile0 = (blockIdx.x % segs) * MT_D;
    const int t = threadIdx.x;
    const int wave = t >> 6, lane = t & 63;
    const int col = lane & 15, quad = lane >> 4;
    const int wm = wave & 1, wn = wave >> 1;

    int srow[4], soff[4];
#pragma unroll
    for (int i = 0; i < 4; i++) {
        int c = wave * 256 + i * 64 + lane;
        int r = c >> 4, cc = c & 15;
        srow[i] = r;
        soff[i] = (cc ^ (r & 7)) * 16;
    }

    bf16x8 b[4][4];
    {
        const unsigned short* wb = WdT + (long)bk * CDOWN * CDOWN;
#pragma unroll
        for (int kk = 0; kk < 4; kk++)
#pragma unroll
            for (int nt = 0; nt < 4; nt++)
                b[kk][nt] = *(const bf16x8*)&wb[(wn * 64 + nt * 16 + col) * CDOWN + kk * 32 + quad * 8];
    }

    const long kBase = (long)bk * NDOWN;
    const char* sAc = (const char*)sA;

    for (int tt = 0; tt < MT_D; ++tt) {
        const int rowbase = (tile0 + tt) * TM;
#pragma unroll
        for (int i = 0; i < 4; i++) {
            const int j = in_idx[kBase + rowbase + srow[i]];
            gll16((const char*)dbf + (long)j * (CDOWN * 2) + soff[i],
                  (char*)sA + (wave * 4 + i) * 1024);
        }
        __syncthreads();

        f32x4 acc[2][4];
#pragma unroll
        for (int mi = 0; mi < 2; mi++)
#pragma unroll
            for (int nt = 0; nt < 4; nt++) acc[mi][nt] = (f32x4){0.f, 0.f, 0.f, 0.f};

#pragma unroll
        for (int kk = 0; kk < 4; kk++) {
            const int ch = kk * 4 + quad;
#pragma unroll
            for (int mi = 0; mi < 2; mi++) {
                const int row = wm * 32 + mi * 16 + col;
                bf16x8 a = *(const bf16x8*)(sAc + row * 256 + ((ch ^ (row & 7)) * 16));
#pragma unroll
                for (int nt = 0; nt < 4; nt++)
                    acc[mi][nt] = __builtin_amdgcn_mfma_f32_16x16x32_bf16(a, b[kk][nt], acc[mi][nt], 0, 0, 0);
            }
        }
        __syncthreads();

#pragma unroll
        for (int mi = 0; mi < 2; mi++)
#pragma unroll
            for (int r = 0; r < 4; r++) {
                const int lrow = wm * 32 + mi * 16 + quad * 4 + r;
                const long ob = (long)out_idx[kBase + rowbase + lrow] * CDOWN;
#pragma unroll
                for (int nt = 0; nt < 4; nt++)
                    atomicAdd(&up[ob + wn * 64 + nt * 16 + col], acc[mi][nt][r]);
            }
    }
}

// ---------------- inverse-CSR build ----------------
__global__ void hist_kernel(const int* __restrict__ cv_out, unsigned int* __restrict__ hist) {
    const int i = blockIdx.x * 256 + threadIdx.x;
    const int k = blockIdx.y;
    const int j = cv_out[(long)k * NUP + i];
    atomicAdd(&hist[(long)k * NUP + j], 1u);
}

__global__ void scan_blocks(const unsigned int* __restrict__ in, unsigned int* __restrict__ out,
                            unsigned int* __restrict__ aux, int n) {
    __shared__ unsigned int ls[256];
    const int t = threadIdx.x;
    const long base = (long)blockIdx.x * 1024 + (long)t * 4;
    unsigned int v0 = (base     < n) ? in[base]     : 0u;
    unsigned int v1 = (base + 1 < n) ? in[base + 1] : 0u;
    unsigned int v2 = (base + 2 < n) ? in[base + 2] : 0u;
    unsigned int v3 = (base + 3 < n) ? in[base + 3] : 0u;
    const unsigned int s = v0 + v1 + v2 + v3;
    ls[t] = s;
    __syncthreads();
    for (int off = 1; off < 256; off <<= 1) {
        unsigned int x = (t >= off) ? ls[t - off] : 0u;
        __syncthreads();
        ls[t] += x;
        __syncthreads();
    }
    const unsigned int ex = ls[t] - s;
    if (base     < n) out[base]     = ex;
    if (base + 1 < n) out[base + 1] = ex + v0;
    if (base + 2 < n) out[base + 2] = ex + v0 + v1;
    if (base + 3 < n) out[base + 3] = ex + v0 + v1 + v2;
    if (aux != nullptr && t == 255) aux[blockIdx.x] = ls[255];
}

// fused mid-level: in-place exclusive scan of aux1 (n ~ 4219), single block
__global__ void scan_mid(unsigned int* __restrict__ a, int n) {
    __shared__ unsigned int ls[256];
    __shared__ unsigned int carry;
    const int t = threadIdx.x;
    if (t == 0) carry = 0u;
    __syncthreads();
    for (int base = 0; base < n; base += 256) {
        const int idx = base + t;
        unsigned int v = (idx < n) ? a[idx] : 0u;
        ls[t] = v;
        __syncthreads();
        for (int off = 1; off < 256; off <<= 1) {
            unsigned int x = (t >= off) ? ls[t - off] : 0u;
            __syncthreads();
            ls[t] += x;
            __syncthreads();
        }
        const unsigned int ex = ls[t] - v + carry;
        if (idx < n) a[idx] = ex;
        __syncthreads();
        if (t == 0) carry += ls[255];
        __syncthreads();
    }
}

__global__ void addback_kernel(unsigned int* __restrict__ out, const unsigned int* __restrict__ aux, int n) {
    const long i = (long)blockIdx.x * 256 + threadIdx.x;
    if (i < n) out[i] += aux[i >> 10];
}

__global__ void scatter_kernel(const int* __restrict__ cv_in,
                               const int* __restrict__ cv_out,
                               const unsigned int* __restrict__ start,
                               unsigned int* __restrict__ hist,       // counts, consumed
                               unsigned int* __restrict__ entries) {
    const int i = blockIdx.x * 256 + threadIdx.x;
    const int k = blockIdx.y;
    const long p = (long)k * NUP + i;
    const int j = cv_out[p];
    const long bin = (long)k * NUP + j;
    const unsigned int off = atomicSub(&hist[bin], 1u) - 1u;
    entries[start[bin] + off] = (unsigned int)cv_in[p];
}

// ---------------- conv v3: gather form with 3-stage software-pipelined produce ----------------
// META(k+3): start[] pair -> (s0,n).  EIDX(k+2): up to 6 entry indices (independent loads).
// DATA(k+1): cat chunk loads (ALL independent, indices prefetched), f32 dup-sum in e-order,
//            swizzled LDS write to buf[(k+1)&1].  MFMA(k): buf[k&1].  One barrier/iter.
__global__ __launch_bounds__(256, 3)
void conv_inv(const unsigned short* __restrict__ cat,
              const unsigned short* __restrict__ WcT,
              const unsigned int* __restrict__ start,
              const unsigned int* __restrict__ entries,
              float* __restrict__ out) {
    __shared__ __align__(1024) unsigned short sA[2][TM * CCAT];   // 48 KB double-buffered A

    const int j0 = blockIdx.x * TM;
    const int t = threadIdx.x;
    const int wave = t >> 6, lane = t & 63;
    const int col = lane & 15, quad = lane >> 4;
    const int wm = wave & 1, wn = wave >> 1;
    const int r  = t >> 2;           // staging row 0..63 (4 threads/row)
    const int cq = (t & 3) * 6;      // staging chunk base (6 chunks of 16B)

    // --- pipeline helpers (all state in named registers, static indexing) ---
    auto meta = [&](int kp, unsigned int& s0, unsigned int& n) {
        const long idx = (long)kp * NUP + j0 + r;
        const unsigned int a = start[idx];
        const unsigned int b = (idx + 1 == (long)B_BINS) ? (unsigned int)B_BINS : start[idx + 1];
        s0 = a; n = b - a;
    };
    auto eidxf = [&](unsigned int s0, unsigned int n, unsigned int* e) {
#pragma unroll
        for (int j = 0; j < 6; j++) e[j] = (j < (int)n) ? entries[s0 + j] : 0u;
    };
    auto data = [&](int buf, unsigned int s0, unsigned int n, const unsigned int* e) {
        char* dst = (char*)sA[buf] + r * 384;
        if (n == 1u) {                               // common: straight bf16 chunk copies
            const uint4* src = (const uint4*)(cat + (long)e[0] * CCAT) + cq;
#pragma unroll
            for (int q = 0; q < 6; q++)
                *(uint4*)(dst + (((cq + q) ^ (r & 7)) << 4)) = src[q];
        } else if (n == 0u) {
            const uint4 z = make_uint4(0u, 0u, 0u, 0u);
#pragma unroll
            for (int q = 0; q < 6; q++)
                *(uint4*)(dst + (((cq + q) ^ (r & 7)) << 4)) = z;
        } else {                                     // dup rows: independent loads, e-order f32 sum
            const uint4* p0 = (const uint4*)(cat + (long)e[0] * CCAT) + cq;
            const uint4* p1 = (const uint4*)(cat + (long)e[1] * CCAT) + cq;
            const uint4* p2 = (const uint4*)(cat + (long)e[2] * CCAT) + cq;
            const uint4* p3 = (const uint4*)(cat + (long)e[3] * CCAT) + cq;
            const uint4* p4 = (const uint4*)(cat + (long)e[4] * CCAT) + cq;
            const uint4* p5 = (const uint4*)(cat + (long)e[5] * CCAT) + cq;
#pragma unroll
            for (int q = 0; q < 6; q++) {
                float fa[8];
#pragma unroll
                for (int x = 0; x < 8; x++) fa[x] = 0.f;
                addchunk(fa, p0[q]);
                addchunk(fa, p1[q]);
                if (n > 2u) addchunk(fa, p2[q]);
                if (n > 3u) addchunk(fa, p3[q]);
                if (n > 4u) addchunk(fa, p4[q]);
                if (n > 5u) addchunk(fa, p5[q]);
                for (unsigned int ee = s0 + 6u; ee < s0 + n; ee++) {   // very rare tail
                    const uint4 c = ((const uint4*)(cat + (long)entries[ee] * CCAT))[cq + q];
                    addchunk(fa, c);
                }
                uint4 o;
                o.x = pk2(fa[0], fa[1]); o.y = pk2(fa[2], fa[3]);
                o.z = pk2(fa[4], fa[5]); o.w = pk2(fa[6], fa[7]);
                *(uint4*)(dst + (((cq + q) ^ (r & 7)) << 4)) = o;
            }
        }
    };

    f32x4 acc[2][3];
#pragma unroll
    for (int mi = 0; mi < 2; mi++)
#pragma unroll
        for (int nt = 0; nt < 3; nt++) acc[mi][nt] = (f32x4){0.f, 0.f, 0.f, 0.f};

    // --- prologue: fill pipeline ---
    unsigned int s0_0, n_0;  meta(0, s0_0, n_0);
    unsigned int e0[6];      eidxf(s0_0, n_0, e0);
    unsigned int ma_s0, ma_n, mb_s0, mb_n, mc_s0 = 0, mc_n = 0;
    meta(1, ma_s0, ma_n);
    meta(2, mb_s0, mb_n);
    unsigned int ea[6];      eidxf(ma_s0, ma_n, ea);      // EIDX(1)
    unsigned int eb[6];
#pragma unroll
    for (int j = 0; j < 6; j++) eb[j] = 0u;
    data(0, s0_0, n_0, e0);                               // DATA(0) -> buf0

    const unsigned short* wl = WcT + (long)(wn * 48 + col) * CCAT + quad * 8;
    const int row0 = wm * 32 + col, row1 = row0 + 16;

    for (int k = 0; k < K_OFF; k++) {
        __syncthreads();                                  // DATA(k) visible; buf[(k+1)&1] free
        if (k + 3 < K_OFF) meta(k + 3, mc_s0, mc_n);      // META(k+3)
        if (k + 2 < K_OFF) eidxf(mb_s0, mb_n, eb);        // EIDX(k+2)
        if (k + 1 < K_OFF) data((k + 1) & 1, ma_s0, ma_n, ea);  // DATA(k+1)

        const unsigned short* wk = wl + (long)k * (COUT * CCAT);
        const char* cur = (const char*)sA[k & 1];
#pragma unroll
        for (int kk = 0; kk < 6; kk++) {
            bf16x8 b0 = *(const bf16x8*)(wk + kk * 32);
            bf16x8 b1 = *(const bf16x8*)(wk + 16 * CCAT + kk * 32);
            bf16x8 b2 = *(const bf16x8*)(wk + 32 * CCAT + kk * 32);
            const int c2 = kk * 4 + quad;
            bf16x8 a0 = *(const bf16x8*)(cur + row0 * 384 + ((c2 ^ (row0 & 7)) << 4));
            bf16x8 a1 = *(const bf16x8*)(cur + row1 * 384 + ((c2 ^ (row1 & 7)) << 4));
            acc[0][0] = __builtin_amdgcn_mfma_f32_16x16x32_bf16(a0, b0, acc[0][0], 0, 0, 0);
            acc[1][0] = __builtin_amdgcn_mfma_f32_16x16x32_bf16(a1, b0, acc[1][0], 0, 0, 0);
            acc[0][1] = __builtin_amdgcn_mfma_f32_16x16x32_bf16(a0, b1, acc[0][1], 0, 0, 0);
            acc[1][1] = __builtin_amdgcn_mfma_f32_16x16x32_bf16(a1, b1, acc[1][1], 0, 0, 0);
            acc[0][2] = __builtin_amdgcn_mfma_f32_16x16x32_bf16(a0, b2, acc[0][2], 0, 0, 0);
            acc[1][2] = __builtin_amdgcn_mfma_f32_16x16x32_bf16(a1, b2, acc[1][2], 0, 0, 0);
        }

        // rotate pipeline state (static moves)
        ma_s0 = mb_s0; ma_n = mb_n;
        mb_s0 = mc_s0; mb_n = mc_n;
#pragma unroll
        for (int j = 0; j < 6; j++) ea[j] = eb[j];
    }

    // fused ReLU + plain coalesced stores, full coverage (no memset of out needed)
#pragma unroll
    for (int mi = 0; mi < 2; mi++)
#pragma unroll
        for (int rr = 0; rr < 4; rr++) {
            const int lrow = wm * 32 + mi * 16 + quad * 4 + rr;
            float* op = out + (long)(j0 + lrow) * COUT + wn * 48 + col;
#pragma unroll
            for (int nt = 0; nt < 3; nt++)
                op[nt * 16] = fmaxf(acc[mi][nt][rr], 0.f);
        }
}

// ================= fallback path (ws too small) =================
#define SA1 136
#define SB1 136

__global__ __launch_bounds__(256, 2)
void deconv_kernel(const float* __restrict__ down,
                   const float* __restrict__ Wd,
                   const int* __restrict__ in_idx,
                   const int* __restrict__ out_idx,
                   float* __restrict__ up) {
    __shared__ __align__(16) unsigned short sA[TM * SA1];
    __shared__ __align__(16) unsigned short sB[CDOWN * SB1];
    __shared__ int sOut[TM];

    const int tiles = NDOWN / TM;
    const int bk = blockIdx.x / tiles;
    const int tile = blockIdx.x % tiles;
    const int t = threadIdx.x;
    const long kInBase = (long)bk * NDOWN + tile * TM;

    {
        const int r = t >> 2;
        const int c0 = (t & 3) * 32;
        const int j = in_idx[kInBase + r];
        const float* src = down + (long)j * CDOWN + c0;
        unsigned short* dst = sA + r * SA1 + c0;
        #pragma unroll
        for (int c = 0; c < 32; c += 4) {
            float4 v = *(const float4*)(src + c);
            *(unsigned int*)(dst + c)     = pk2(v.x, v.y);
            *(unsigned int*)(dst + c + 2) = pk2(v.z, v.w);
        }
    }
    {
        const float* wsrc = Wd + (long)bk * CDOWN * CDOWN;
        for (int idx = t; idx < CDOWN * CDOWN; idx += 256) {
            const int kk = idx >> 7;
            const int n  = idx & 127;
            sB[n * SB1 + kk] = f2b(wsrc[idx]);
        }
    }
    if (t < TM) sOut[t] = out_idx[kInBase + t];
    __syncthreads();

    const int wave = t >> 6;
    const int lane = t & 63;
    const int col  = lane & 15;
    const int quad = lane >> 4;
    const int mrow = wave * 16 + col;

    f32x4 acc[8];
    #pragma unroll
    for (int i = 0; i < 8; i++) acc[i] = (f32x4){0.f, 0.f, 0.f, 0.f};

    #pragma unroll
    for (int k0 = 0; k0 < CDOWN; k0 += 32) {
        const int koff = k0 + quad * 8;
        bf16x8 a = *(const bf16x8*)&sA[mrow * SA1 + koff];
        #pragma unroll
        for (int nt = 0; nt < 8; nt++) {
            bf16x8 bb = *(const bf16x8*)&sB[(nt * 16 + col) * SB1 + koff];
            acc[nt] = __builtin_amdgcn_mfma_f32_16x16x32_bf16(a, bb, acc[nt], 0, 0, 0);
        }
    }
    #pragma unroll
    for (int r = 0; r < 4; r++) {
        const int lrow = wave * 16 + quad * 4 + r;
        const long obase = (long)sOut[lrow] * CDOWN;
        #pragma unroll
        for (int nt = 0; nt < 8; nt++)
            atomicAdd(&up[obase + nt * 16 + col], acc[nt][r]);
    }
}

#define SA2 200
#define SB2 200

__global__ __launch_bounds__(256, 2)
void conv_kernel(const float* __restrict__ up,
                 const float* __restrict__ skip,
                 const float* __restrict__ Wc,
                 const int* __restrict__ in_idx,
                 const int* __restrict__ out_idx,
                 float* __restrict__ out) {
    __shared__ __align__(16) unsigned short sA[TM * SA2];
    __shared__ __align__(16) unsigned short sB[COUT * SB2];
    __shared__ int sOut[TM];

    const int tiles = NUP / TM;
    const int bk = blockIdx.x / tiles;
    const int tile = blockIdx.x % tiles;
    const int t = threadIdx.x;
    const long kInBase = (long)bk * NUP + tile * TM;

    {
        const int r = t >> 2;
        const int c0 = (t & 3) * 48;
        const int j = in_idx[kInBase + r];
        const float* uprow = up + (long)j * CDOWN;
        const float* skrow = skip + (long)j * CSKIP;
        unsigned short* dst = sA + r * SA2 + c0;
        #pragma unroll
        for (int c = 0; c < 48; c += 4) {
            const int gc = c0 + c;
            float4 v;
            if (gc < CDOWN) {
                v = *(const float4*)(uprow + gc);
                v.x = fmaxf(v.x, 0.f); v.y = fmaxf(v.y, 0.f);
                v.z = fmaxf(v.z, 0.f); v.w = fmaxf(v.w, 0.f);
            } else {
                v = *(const float4*)(skrow + (gc - CDOWN));
            }
            *(unsigned int*)(dst + c)     = pk2(v.x, v.y);
            *(unsigned int*)(dst + c + 2) = pk2(v.z, v.w);
        }
    }
    {
        const float* wsrc = Wc + (long)bk * CCAT * COUT;
        for (int idx = t; idx < CCAT * COUT; idx += 256) {
            const int kk = idx / COUT;
            const int n  = idx - kk * COUT;
            sB[n * SB2 + kk] = f2b(wsrc[idx]);
        }
    }
    if (t < TM) sOut[t] = out_idx[kInBase + t];
    __syncthreads();

    const int wave = t >> 6;
    const int lane = t & 63;
    const int col  = lane & 15;
    const int quad = lane >> 4;
    const int mrow = wave * 16 + col;

    f32x4 acc[6];
    #pragma unroll
    for (int i = 0; i < 6; i++) acc[i] = (f32x4){0.f, 0.f, 0.f, 0.f};

    #pragma unroll
    for (int k0 = 0; k0 < CCAT; k0 += 32) {
        const int koff = k0 + quad * 8;
        bf16x8 a = *(const bf16x8*)&sA[mrow * SA2 + koff];
        #pragma unroll
        for (int nt = 0; nt < 6; nt++) {
            bf16x8 bb = *(const bf16x8*)&sB[(nt * 16 + col) * SB2 + koff];
            acc[nt] = __builtin_amdgcn_mfma_f32_16x16x32_bf16(a, bb, acc[nt], 0, 0, 0);
        }
    }
    #pragma unroll
    for (int r = 0; r < 4; r++) {
        const int lrow = wave * 16 + quad * 4 + r;
        const long obase = (long)sOut[lrow] * COUT;
        #pragma unroll
        for (int nt = 0; nt < 6; nt++)
            atomicAdd(&out[obase + nt * 16 + col], acc[nt][r]);
    }
}

__global__ void relu_kernel(float* __restrict__ x, int n4) {
    int i = blockIdx.x * blockDim.x + threadIdx.x;
    if (i < n4) {
        float4 v = ((float4*)x)[i];
        v.x = fmaxf(v.x, 0.f); v.y = fmaxf(v.y, 0.f);
        v.z = fmaxf(v.z, 0.f); v.w = fmaxf(v.w, 0.f);
        ((float4*)x)[i] = v;
    }
}

extern "C" void kernel_launch(void* const* d_in, const int* in_sizes, int n_in,
                              void* d_out, int out_size, void* d_ws, size_t ws_size,
                              hipStream_t stream) {
    const float* skip   = (const float*)d_in[0];
    const float* down   = (const float*)d_in[1];
    const float* Wd     = (const float*)d_in[2];
    const float* Wc     = (const float*)d_in[3];
    const int* dc_in    = (const int*)d_in[4];
    const int* dc_out   = (const int*)d_in[5];
    const int* cv_in    = (const int*)d_in[6];
    const int* cv_out   = (const int*)d_in[7];
    float* out = (float*)d_out;
    float* up  = (float*)d_ws;                   // [NUP][CDOWN] f32, dead after pack_cat

    const size_t OFF_CAT = (size_t)NUP * CDOWN * 4;                    //  81,920,000
    const size_t OFF_DBF = OFF_CAT + (size_t)NUP * CCAT * 2;           // 143,360,000
    const size_t OFF_WDT = OFF_DBF + (size_t)NDOWN * CDOWN * 2;        // 153,600,000
    const size_t OFF_WCT = OFF_WDT + (size_t)K_OFF * CDOWN * CDOWN * 2;// 154,484,736
    const size_t WS_NEED = OFF_WCT + (size_t)K_OFF * COUT * CCAT * 2;  // 155,480,064

    hipMemsetAsync(up, 0, (size_t)NUP * CDOWN * sizeof(float), stream);

    if (ws_size >= WS_NEED) {
        unsigned short* catb = (unsigned short*)((char*)d_ws + OFF_CAT);
        unsigned short* dbf  = (unsigned short*)((char*)d_ws + OFF_DBF);
        unsigned short* WdT  = (unsigned short*)((char*)d_ws + OFF_WDT);
        unsigned short* WcT  = (unsigned short*)((char*)d_ws + OFF_WCT);

        // CSR scratch overlays the `up` region (touched only AFTER pack_cat);
        // histogram overlays d_out (conv_inv rewrites every element afterwards).
        unsigned int* entriesC = (unsigned int*)d_ws;                           // 17.28 MB
        unsigned int* startC   = (unsigned int*)((char*)d_ws + 17280000);       // 17.28 MB
        unsigned int* aux1     = (unsigned int*)((char*)d_ws + 34560000);       // 4219*4 B
        unsigned int* hist     = (unsigned int*)d_out;                          // 17.28 MB

        pack_all_kernel<<<2500, 256, 0, stream>>>(down, Wd, Wc, dbf, WdT, WcT);
        deconv_fast<<<K_OFF * ((NDOWN / TM) / MT_D), 256, 0, stream>>>(dbf, WdT, dc_in, dc_out, up);
        pack_cat_kernel<<<NUP / 8, 192, 0, stream>>>(up, skip, catb);
        // ---- up region now dead; build inverse CSR for conv ----
        hipMemsetAsync(hist, 0, (size_t)B_BINS * 4, stream);
        hist_kernel<<<dim3(NUP / 256, K_OFF), 256, 0, stream>>>(cv_out, hist);
        const int nblk1 = (B_BINS + 1023) / 1024;                // 4219
        scan_blocks<<<nblk1, 256, 0, stream>>>(hist, startC, aux1, B_BINS);
        scan_mid<<<1, 256, 0, stream>>>(aux1, nblk1);
        addback_kernel<<<(B_BINS + 255) / 256, 256, 0, stream>>>(startC, aux1, B_BINS);
        scatter_kernel<<<dim3(NUP / 256, K_OFF), 256, 0, stream>>>(cv_in, cv_out, startC, hist, entriesC);
        // ---- gather-form conv: no atomics, fused ReLU, full-coverage stores ----
        conv_inv<<<NUP / TM, 256, 0, stream>>>(catb, WcT, startC, entriesC, out);
    } else {
        hipMemsetAsync(out, 0, (size_t)out_size * sizeof(float), stream);
        deconv_kernel<<<K_OFF * (NDOWN / TM), 256, 0, stream>>>(down, Wd, dc_in, dc_out, up);
        conv_kernel<<<K_OFF * (NUP / TM), 256, 0, stream>>>(up, skip, Wc, cv_in, cv_out, out);
        relu_kernel<<<(out_size / 4 + 255) / 256, 256, 0, stream>>>(out, out_size / 4);
    }
}